// Round 11
// baseline (72.298 us; speedup 1.0000x reference)
//
#include <hip/hip_runtime.h>

// Problem constants (from reference setup_inputs)
#define NN 8
#define CC 4
#define HH 64
#define WW 64
#define KK 5
#define FF 16
#define HO 60
#define WO 60
#define PP (KK * KK * CC) /* 100 */

#define RPB 2              /* output rows per block/wave */
#define HPB (HO / RPB)     /* 30 ho-pairs */
#define RIN (RPB + KK - 1) /* 6 input rows per channel */

typedef float v4f __attribute__((ext_vector_type(4)));

#define PQ_ELEMS (CC * RIN * 64) /* 1536 */
#define LDS_TOT (PQ_ELEMS + 4)   /* red overlay needs exactly 1536 v4f */

// ws layout: per (fq,fp,c): 25 records x 8 floats, [kh][kw][8] with per-kh
// 40 floats CONTIGUOUS (2-3 s_load_dwordx16 per kh, ONE drain point).
// j in record: {eA1(f0),eA1(f1),bA1(f0),bA1(f1),eA2(f0),eA2(f1),bA2(f0),bA2(f1)}
// where A1=e^k1, bA1=k1 e^k1 etc., f0 = fq*4+fp*2, f1 = f0+1.
__global__ void smorph_weights(const float* __restrict__ k1,
                               const float* __restrict__ k2,
                               float* __restrict__ wq) {
    int i = blockIdx.x * blockDim.x + threadIdx.x;
    if (i < 6400) {
        int rec = i >> 3, j = i & 7;
        int cfp = rec / 25, khkw = rec - cfp * 25;
        int kh = khkw / 5, kw = khkw - kh * 5;
        int fqfp = cfp >> 2, c = cfp & 3;
        int fq = fqfp >> 1, fp = fqfp & 1;
        int ff = j & 1, grp = j >> 1; // 0:eA1 1:bA1 2:eA2 3:bA2
        int f = fq * 4 + fp * 2 + ff;
        int p = (kh * KK + kw) * CC + c; // reference patch order (kh,kw,c)
        const float* kp = (grp >> 1) ? k2 : k1;
        float kv = kp[p * FF + f];
        float e = __expf(kv);
        wq[i] = (grp & 1) ? kv * e : e;
    }
}

// Round-11: R1/R7/R9/R10 all ~70.7-71.5 (kernel 18-20us); R8 decomposition:
// steady S~10.5us (at 27% occ, RPB=2) + in-kernel ramp R~10us. Each prior fix
// was partial: LDS-weights -> LDS-pipe bound; RPB=1 scalar weights -> 25
// correlated lgkm(0) drains/wave; RPB=2 -> low occupancy. This round combines:
// RPB=2 (weight+pixel amortization) + 960 blocks (n x hp x fq; ~30 waves/CU,
// all co-resident at 24.6 KB LDS) + scalar weights with per-kh CONTIGUOUS
// 40-float records (1 drain/kh, s_loads issued before the batched pixel
// ds_reads so DS issue overlaps K$ latency) + register row-carry (30 b128/
// wave/tile) + single-shot reduction (both rows packed, 2 barriers).
__global__ __launch_bounds__(512) void smorph_conv(
        const float* __restrict__ x, const float* __restrict__ wq,
        const float* __restrict__ bias, float* __restrict__ out) {
    __shared__ v4f lds[LDS_TOT];
    v4f* pq = lds; // [c][rin 6][64] pixel quads {e^x, x e^x, e^-x, -x e^-x}

    int b = blockIdx.x; // 0..959 = (n, hp, fq); fq fastest: 4 blocks share x
    int n = b / (HPB * 4);
    int rem = b - n * (HPB * 4);
    int hp = rem >> 2;
    int fq = rem & 3; // feature quad: features 4fq..4fq+3
    int ho0 = hp * RPB;
    int t = threadIdx.x;

    // Stage pixel exp-quads: input rows ho0..ho0+5 (<=63), all c, w 0..63.
    for (int i = t; i < PQ_ELEMS; i += 512) {
        int w = i & 63;
        int cr = i >> 6; // c*RIN + r
        int c = cr / RIN, r = cr - c * RIN;
        float v = x[((n * CC + c) * HH + (ho0 + r)) * WW + w];
        float e1 = __expf(v), e2 = __expf(-v);
        pq[i] = (v4f){e1, v * e1, e2, -v * e2};
    }
    __syncthreads();

    int lane = t & 63; // w position (60 used)
    int wid = t >> 6;  // 0..7
    int cw = wid & 3;  // channel owned by this wave
    int fp = wid >> 2; // f-pair within quad: features fq*4+fp*2, +1

    // Wave-uniform scalar weight base (25 records x 8 floats for (fq,fp,cw)).
    int wbo = __builtin_amdgcn_readfirstlane(((fq * 2 + fp) * CC + cw) * 200);
    const float* wb = wq + wbo;

    float d1[RPB][2], n1[RPB][2], d2[RPB][2], n2[RPB][2]; // [row][ff]
#pragma unroll
    for (int r = 0; r < RPB; ++r)
#pragma unroll
        for (int ff = 0; ff < 2; ++ff) {
            d1[r][ff] = 0.f; n1[r][ff] = 0.f;
            d2[r][ff] = 0.f; n2[r][ff] = 0.f;
        }

    const v4f* pbase = pq + (cw * RIN) * 64 + lane;

    v4f qprev[KK]; // input row kh (row-carry across kh)
#pragma unroll
    for (int kw = 0; kw < KK; ++kw) qprev[kw] = pbase[kw];

#pragma unroll 1
    for (int kh = 0; kh < KK; ++kh) {
        // 1) Issue this kh's 40 uniform weight floats (s_load_dwordx16 x2.5,
        //    one lgkm drain group) ...
        const float* wk = wb + kh * 40;
        float wv[40];
#pragma unroll
        for (int j = 0; j < 40; ++j) wv[j] = wk[j];
        // 2) ... overlap with the 5 batched pixel ds_reads for row kh+1.
        const v4f* prow = pbase + (kh + 1) * 64;
        v4f qn[KK];
#pragma unroll
        for (int kw = 0; kw < KK; ++kw) qn[kw] = prow[kw];
        // 3) 120 fmas, weights from SGPRs (single scalar operand per fma).
#pragma unroll
        for (int kw = 0; kw < KK; ++kw) {
            v4f q = qprev[kw], qq = qn[kw];
#pragma unroll
            for (int ff = 0; ff < 2; ++ff) {
                float eA1 = wv[kw * 8 + ff],     bA1 = wv[kw * 8 + 2 + ff];
                float eA2 = wv[kw * 8 + 4 + ff], bA2 = wv[kw * 8 + 6 + ff];
                d1[0][ff] = fmaf(q.x, eA1, d1[0][ff]);
                n1[0][ff] = fmaf(q.y, eA1, n1[0][ff]);
                n1[0][ff] = fmaf(q.x, bA1, n1[0][ff]);
                d2[0][ff] = fmaf(q.z, eA2, d2[0][ff]);
                n2[0][ff] = fmaf(q.w, eA2, n2[0][ff]);
                n2[0][ff] = fmaf(q.z, bA2, n2[0][ff]);
                d1[1][ff] = fmaf(qq.x, eA1, d1[1][ff]);
                n1[1][ff] = fmaf(qq.y, eA1, n1[1][ff]);
                n1[1][ff] = fmaf(qq.x, bA1, n1[1][ff]);
                d2[1][ff] = fmaf(qq.z, eA2, d2[1][ff]);
                n2[1][ff] = fmaf(qq.w, eA2, n2[1][ff]);
                n2[1][ff] = fmaf(qq.z, bA2, n2[1][ff]);
            }
            qprev[kw] = qn[kw]; // row-carry
        }
    }

    // 4-way c-reduction, BOTH rows in one shot (16 floats/thread = 4 v4f).
    // red[(cw-1)*2+fp][acc 0..3][lane]: 3*2*4*64 = 1536 v4f (pq dead).
    v4f* red = lds;
    __syncthreads();
    if (cw) {
        v4f* rr = red + (((cw - 1) * 2 + fp) * 4) * 64 + lane;
        rr[0 * 64] = (v4f){d1[0][0], d1[0][1], d1[1][0], d1[1][1]};
        rr[1 * 64] = (v4f){n1[0][0], n1[0][1], n1[1][0], n1[1][1]};
        rr[2 * 64] = (v4f){d2[0][0], d2[0][1], d2[1][0], d2[1][1]};
        rr[3 * 64] = (v4f){n2[0][0], n2[0][1], n2[1][0], n2[1][1]};
    }
    __syncthreads();
    if (!cw && lane < WO) {
#pragma unroll
        for (int rcw = 0; rcw < 3; ++rcw) {
            const v4f* rr = red + ((rcw * 2 + fp) * 4) * 64 + lane;
            v4f t0 = rr[0 * 64], t1 = rr[1 * 64];
            v4f t2 = rr[2 * 64], t3 = rr[3 * 64];
            d1[0][0] += t0.x; d1[0][1] += t0.y; d1[1][0] += t0.z; d1[1][1] += t0.w;
            n1[0][0] += t1.x; n1[0][1] += t1.y; n1[1][0] += t1.z; n1[1][1] += t1.w;
            d2[0][0] += t2.x; d2[0][1] += t2.y; d2[1][0] += t2.z; d2[1][1] += t2.w;
            n2[0][0] += t3.x; n2[0][1] += t3.y; n2[1][0] += t3.z; n2[1][1] += t3.w;
        }
#pragma unroll
        for (int r = 0; r < RPB; ++r)
#pragma unroll
            for (int ff = 0; ff < 2; ++ff) {
                int f = fq * 4 + fp * 2 + ff;
                float o = n1[r][ff] / d1[r][ff] + n2[r][ff] / d2[r][ff] + bias[f];
                out[((size_t)(n * FF + f) * HO + (ho0 + r)) * WO + lane] = o;
            }
    }
}

extern "C" void kernel_launch(void* const* d_in, const int* in_sizes, int n_in,
                              void* d_out, int out_size, void* d_ws, size_t ws_size,
                              hipStream_t stream) {
    const float* x    = (const float*)d_in[0];
    const float* k1   = (const float*)d_in[1];
    const float* k2   = (const float*)d_in[2];
    const float* bias = (const float*)d_in[3];
    float* out = (float*)d_out;
    float* wq = (float*)d_ws; // 6400 floats = 25.6 KB

    smorph_weights<<<25, 256, 0, stream>>>(k1, k2, wq);
    // 960 blocks = 8 n x 30 ho-pairs x 4 f-quads; 512 threads = 8 waves
    // (4 c x 2 f-pairs), each wave: 2 rows x 2 features x 1 channel.
    smorph_conv<<<NN * HPB * 4, 512, 0, stream>>>(x, wq, bias, out);
}